// Round 11
// baseline (182.590 us; speedup 1.0000x reference)
//
#include <hip/hip_runtime.h>
#include <hip/hip_cooperative_groups.h>
#include <math.h>

namespace cg = cooperative_groups;

#define LFFT 16384
#define NTHREADS 1024
#define LDS_PITCH 17   // float2 per row (16 + 1 pad); stride 34 banks == 2 mod 32

// Wave-local LDS ordering fence.
#define LDS_FENCE() asm volatile("s_waitcnt lgkmcnt(0)" ::: "memory")

__device__ __forceinline__ float2 cadd(float2 a, float2 b){ return make_float2(a.x+b.x, a.y+b.y); }
__device__ __forceinline__ float2 csub(float2 a, float2 b){ return make_float2(a.x-b.x, a.y-b.y); }
__device__ __forceinline__ float2 cmul(float2 a, float2 b){ return make_float2(a.x*b.x - a.y*b.y, a.x*b.y + a.y*b.x); }

template<int S> __device__ __forceinline__ float2 mul_is(float2 a) {
    return make_float2(-(float)S * a.y, (float)S * a.x);
}

// Radix-4 butterfly. S=-1 fwd, S=+1 inverse (unnormalized).
template<int S> __device__ __forceinline__ void dft4_t(float2& a0, float2& a1, float2& a2, float2& a3) {
    float2 t0 = cadd(a0, a2);
    float2 t1 = csub(a0, a2);
    float2 t2 = cadd(a1, a3);
    float2 t3 = csub(a1, a3);
    a0 = cadd(t0, t2);
    a2 = csub(t0, t2);
    const float s = (float)S;
    a1 = make_float2(t1.x - s * t3.y, t1.y + s * t3.x);
    a3 = make_float2(t1.x + s * t3.y, t1.y - s * t3.x);
}

#define C16A 0.92387953251128675613f
#define C16B 0.70710678118654752440f
#define C16C 0.38268343236508977173f

// Fully-unrolled 16-point DFT, natural order in and out.
template<int S> __device__ __forceinline__ void dft16_t(float2 r[16]) {
    const float s = (float)S;
    const float2 w1 = make_float2( C16A, s * C16C);
    const float2 w2 = make_float2( C16B, s * C16B);
    const float2 w3 = make_float2( C16C, s * C16A);
    const float2 w6 = make_float2(-C16B, s * C16B);
    const float2 w9 = make_float2(-C16A, -s * C16C);
    float2 g[4][4];
    #pragma unroll
    for (int b = 0; b < 4; ++b) {
        float2 a0 = r[b], a1 = r[b+4], a2 = r[b+8], a3 = r[b+12];
        dft4_t<S>(a0, a1, a2, a3);
        g[b][0] = a0; g[b][1] = a1; g[b][2] = a2; g[b][3] = a3;
    }
    g[1][1] = cmul(g[1][1], w1);  g[1][2] = cmul(g[1][2], w2);  g[1][3] = cmul(g[1][3], w3);
    g[2][1] = cmul(g[2][1], w2);  g[2][2] = mul_is<S>(g[2][2]); g[2][3] = cmul(g[2][3], w6);
    g[3][1] = cmul(g[3][1], w3);  g[3][2] = cmul(g[3][2], w6);  g[3][3] = cmul(g[3][3], w9);
    #pragma unroll
    for (int ka = 0; ka < 4; ++ka) {
        float2 a0 = g[0][ka], a1 = g[1][ka], a2 = g[2][ka], a3 = g[3][ka];
        dft4_t<S>(a0, a1, a2, a3);
        r[ka] = a0; r[ka+4] = a1; r[ka+8] = a2; r[ka+12] = a3;
    }
}

// r[k] *= w^k, k = 1..15
__device__ __forceinline__ void twiddle15(float2 r[16], float2 w) {
    float2 w2 = cmul(w, w);
    float2 we = w2;
    float2 wo = cmul(w, w2);
    r[1] = cmul(r[1], w);
    r[2] = cmul(r[2], we);
    r[3] = cmul(r[3], wo);
    #pragma unroll
    for (int j = 2; j <= 7; ++j) {
        we = cmul(we, w2);  r[2*j]   = cmul(r[2*j],   we);
        wo = cmul(wo, w2);  r[2*j+1] = cmul(r[2*j+1], wo);
    }
}

// ---------------------------------------------------------------------------
// Single cooperative kernel.
// Phase A (blocks 0..127): table builder (round-10 logic verbatim): 8 threads
//   per output p (e = which eval of K(m)/K(L-m), q = 16-state quarter of the
//   Cauchy sum), tan-identity g = i(2/step)tan(pi m/L), c = 1 + i tan(...);
//   partials reduced through LDS (re-aliased as double scratch);
//   lane (T&7)==0 finalizes + Hermitian-combines Kperm[p]; lane (T&7)==1
//   emits twid[p] = cis(-2 pi p/L).
// grid.sync() (device-scope release/acquire -> tables visible to all XCDs).
// Phase B: champion FFT body byte-identical, looped over 2 row-pairs
//   (rp = blockIdx.x + gridDim.x * it). 256 blocks x 136 KiB LDS = exactly
//   1 block/CU x 256 CUs -> cooperative co-residency holds.
// ---------------------------------------------------------------------------
__global__ __launch_bounds__(NTHREADS, 4) void s4_all(
    const float* __restrict__ x, float* __restrict__ y,
    const float* __restrict__ Lr, const float* __restrict__ Li,
    const float* __restrict__ Pr, const float* __restrict__ Pi,
    const float* __restrict__ Br, const float* __restrict__ Bi,
    const float* __restrict__ Cr, const float* __restrict__ Ci,
    const float* __restrict__ step_ptr,
    float2* __restrict__ Kperm, float2* __restrict__ twid)
{
    __shared__ float2 lds[NTHREADS * LDS_PITCH];   // 136 KiB
    const int t = threadIdx.x;

    // ================= Phase A: tables =================
    {
        double* part = reinterpret_cast<double*>(lds);   // [1024][8] doubles
        const int T = blockIdx.x * NTHREADS + t;
        const bool active = (T < 8 * LFFT);
        double tn = 0.0;
        int p = 0;
        if (active) {
            p = T >> 3;
            const int e = (T >> 2) & 1, q = T & 3;
            int t16 = p >> 4, j = p & 15;
            int m = (t16 >> 6) + 16 * ((t16 >> 2) & 15)
                  + 256 * (4 * (t16 & 3) + (j >> 2)) + 4096 * (j & 3);
            int idx = e ? ((LFFT - m) & (LFFT - 1)) : m;

            const double step = (double)step_ptr[0];
            tn = tan((M_PI / (double)LFFT) * (double)idx);
            const double gi = (2.0 / step) * tn;   // g = i*gi

            double k00r=0,k00i=0,k01r=0,k01i=0,k10r=0,k10i=0,k11r=0,k11i=0;
            const int n0 = 16 * q;
            for (int n = n0; n < n0 + 16; ++n) {
                double dr = -(double)Lr[n];
                double di = gi - (double)Li[n];
                double id2 = 1.0 / (dr*dr + di*di);
                double vr =  dr * id2;
                double vi = -di * id2;
                double a0r = (double)Cr[n], a0i = -(double)Ci[n];
                double a1r = (double)Pr[n], a1i = -(double)Pi[n];
                double br  = (double)Br[n], bi  = (double)Bi[n];
                double pr  = (double)Pr[n], pi  = (double)Pi[n];
                double e00r = a0r*br - a0i*bi, e00i = a0r*bi + a0i*br;
                double e01r = a0r*pr - a0i*pi, e01i = a0r*pi + a0i*pr;
                double e10r = a1r*br - a1i*bi, e10i = a1r*bi + a1i*br;
                double e11r = a1r*pr - a1i*pi, e11i = a1r*pi + a1i*pr;
                k00r += vr*e00r - vi*e00i;  k00i += vr*e00i + vi*e00r;
                k01r += vr*e01r - vi*e01i;  k01i += vr*e01i + vi*e01r;
                k10r += vr*e10r - vi*e10i;  k10i += vr*e10i + vi*e10r;
                k11r += vr*e11r - vi*e11i;  k11i += vr*e11i + vi*e11r;
            }
            double* pp = part + t * 8;
            pp[0] = k00r;  pp[1] = k00i;
            pp[2] = k01r;  pp[3] = k01i;
            pp[4] = k10r;  pp[5] = k10i;
            pp[6] = k11r;  pp[7] = k11i;

            if ((T & 7) == 1) {
                double tth = (-2.0 * M_PI / (double)LFFT) * (double)p;
                double si, co;
                sincos(tth, &si, &co);
                twid[p] = make_float2((float)co, (float)si);
            }
        }
        __syncthreads();
        if (active && (T & 7) == 0) {
            double Kr[2], Ki[2];
            #pragma unroll
            for (int ev = 0; ev < 2; ++ev) {
                double s[8] = {0,0,0,0,0,0,0,0};
                #pragma unroll
                for (int qq = 0; qq < 4; ++qq) {
                    const double* pp = part + (t + 4*ev + qq) * 8;
                    #pragma unroll
                    for (int z = 0; z < 8; ++z) s[z] += pp[z];
                }
                double rr = 1.0 + s[6], ri = s[7];
                double ir2 = 1.0 / (rr*rr + ri*ri);
                double qr0 = s[2]*s[4] - s[3]*s[5];
                double qi0 = s[2]*s[5] + s[3]*s[4];
                double qr = (qr0*rr + qi0*ri) * ir2;
                double qi = (qi0*rr - qr0*ri) * ir2;
                double sr = s[0] - qr, sim = s[1] - qi;
                double tc = (ev == 0) ? tn : -tn;
                Kr[ev] = sr - tc * sim;
                Ki[ev] = sim + tc * sr;
            }
            const float sc = 0.5f / (float)LFFT;
            Kperm[p] = make_float2(sc * (float)(Kr[0] + Kr[1]),
                                   sc * (float)(Ki[0] - Ki[1]));
        }
    }

    __threadfence();            // publish tables at device scope
    cg::this_grid().sync();     // all blocks see complete twid/Kperm

    // ================= Phase B: FFT conv (champion body) =================
    const int lane = t & 63;
    const int w    = t >> 6;
    const int l2   = t & 3;
    const int h    = (t >> 2) & 15;
    const float2* kperm = Kperm;

    for (int it = 0; it < 2; ++it) {
        __syncthreads();   // lds safe to reuse (tables scratch / prev pair IT1)

        const size_t rowbase = ((size_t)blockIdx.x + (size_t)gridDim.x * it) * 2u * LFFT;
        const float* x0 = x + rowbase;
        const float* x1 = x0 + LFFT;

        float2 r[16];

        // ---- load: thread t owns n = t + 1024*a (coalesced) ----
        #pragma unroll
        for (int a = 0; a < 16; ++a)
            r[a] = make_float2(x0[t + NTHREADS*a], x1[t + NTHREADS*a]);

        // ---- P1: DFT-16 over a, twiddle W_16384^(t*k1) ----
        dft16_t<-1>(r);
        twiddle15(r, twid[t]);

        // ---- T1 (cross-wave): r[k] -> (row 64k+lane, col w); read own row ----
        #pragma unroll
        for (int k = 0; k < 16; ++k)
            lds[(k*64 + lane) * LDS_PITCH + w] = r[k];
        __syncthreads();
        #pragma unroll
        for (int a = 0; a < 16; ++a)
            r[a] = lds[t * LDS_PITCH + a];
        LDS_FENCE();   // my reads done before my T2 writes (same stripe)

        // ---- P2: DFT-16 over a2, twiddle W_1024^(lane*k3) ----
        dft16_t<-1>(r);
        twiddle15(r, twid[16 * lane]);

        // ---- T2 (wave-local stripe) ----
        #pragma unroll
        for (int k = 0; k < 16; ++k)
            lds[(w*64 + 4*k + l2) * LDS_PITCH + h] = r[k];
        LDS_FENCE();
        #pragma unroll
        for (int a = 0; a < 16; ++a)
            r[a] = lds[t * LDS_PITCH + a];
        LDS_FENCE();

        // ---- P3: DFT-16 over a3, twiddle W_64^(l2*k5) ----
        dft16_t<-1>(r);
        twiddle15(r, twid[256 * l2]);

        // ---- T3 (wave-local stripe) ----
        #pragma unroll
        for (int k = 0; k < 16; ++k)
            lds[((t & ~3) + (k >> 2)) * LDS_PITCH + 4*(k & 3) + l2] = r[k];
        LDS_FENCE();
        #pragma unroll
        for (int j = 0; j < 16; ++j)
            r[j] = lds[t * LDS_PITCH + j];
        LDS_FENCE();

        // ---- P4: DFT-4 over b3 ----
        #pragma unroll
        for (int q = 0; q < 4; ++q)
            dft4_t<-1>(r[4*q], r[4*q+1], r[4*q+2], r[4*q+3]);

        // ---- pointwise multiply (chunked) ----
        {
            const float4* kp4 = (const float4*)(kperm + t * 16);
            #pragma unroll
            for (int c = 0; c < 2; ++c) {
                float4 kv[4];
                #pragma unroll
                for (int i = 0; i < 4; ++i) kv[i] = kp4[4*c + i];
                #pragma unroll
                for (int i = 0; i < 4; ++i) {
                    r[8*c + 2*i]     = cmul(r[8*c + 2*i],     make_float2(kv[i].x, kv[i].y));
                    r[8*c + 2*i + 1] = cmul(r[8*c + 2*i + 1], make_float2(kv[i].z, kv[i].w));
                }
            }
        }

        // ---- IP4: inverse DFT-4 over k6 ----
        #pragma unroll
        for (int q = 0; q < 4; ++q)
            dft4_t<1>(r[4*q], r[4*q+1], r[4*q+2], r[4*q+3]);

        // ---- IT3 (wave-local stripe) ----
        #pragma unroll
        for (int j = 0; j < 16; ++j)
            lds[((t & ~3) + (j & 3)) * LDS_PITCH + ((4*l2 + (j >> 2)) ^ h)] = r[j];
        LDS_FENCE();
        #pragma unroll
        for (int k = 0; k < 16; ++k)
            r[k] = lds[t * LDS_PITCH + (k ^ h)];
        LDS_FENCE();

        // ---- IP3 ----
        { float2 ww = twid[256 * l2]; twiddle15(r, make_float2(ww.x, -ww.y)); }
        dft16_t<1>(r);

        // ---- IT2 (wave-local stripe) ----
        #pragma unroll
        for (int a = 0; a < 16; ++a)
            lds[(w*64 + l2 + 4*a) * LDS_PITCH + h] = r[a];
        LDS_FENCE();
        #pragma unroll
        for (int k = 0; k < 16; ++k)
            r[k] = lds[t * LDS_PITCH + k];

        // ---- IP2 ----
        { float2 ww = twid[16 * lane]; twiddle15(r, make_float2(ww.x, -ww.y)); }
        dft16_t<1>(r);

        // ---- IT1 (cross-wave): wait all waves' IT2 reads, then exchange ----
        __syncthreads();
        #pragma unroll
        for (int a = 0; a < 16; ++a)
            lds[(lane + 64*a) * LDS_PITCH + w] = r[a];
        __syncthreads();
        #pragma unroll
        for (int k = 0; k < 16; ++k)
            r[k] = lds[t * LDS_PITCH + k];

        // ---- IP1 ----
        { float2 ww = twid[t]; twiddle15(r, make_float2(ww.x, -ww.y)); }
        dft16_t<1>(r);

        // ---- store: Re -> row0, Im -> row1 (coalesced) ----
        float* y0 = y + rowbase;
        float* y1 = y0 + LFFT;
        #pragma unroll
        for (int a = 0; a < 16; ++a) {
            y0[t + NTHREADS*a] = r[a].x;
            y1[t + NTHREADS*a] = r[a].y;
        }
    }
}

extern "C" void kernel_launch(void* const* d_in, const int* in_sizes, int n_in,
                              void* d_out, int out_size, void* d_ws, size_t ws_size,
                              hipStream_t stream)
{
    const float* x  = (const float*)d_in[0];
    const float* Lr = (const float*)d_in[1];
    const float* Li = (const float*)d_in[2];
    const float* Pr = (const float*)d_in[3];
    const float* Pi = (const float*)d_in[4];
    const float* Br = (const float*)d_in[5];
    const float* Bi = (const float*)d_in[6];
    const float* Cr = (const float*)d_in[7];
    const float* Ci = (const float*)d_in[8];
    const float* st = (const float*)d_in[9];
    float* y = (float*)d_out;

    const int rows   = in_sizes[0] / LFFT;  // 1024
    const int blocks = rows / 4;            // 256 = 1 block/CU, 2 row-pairs each

    float2* twid  = (float2*)d_ws;          // LFFT float2 (128 KB)
    float2* Kperm = twid + LFFT;            // LFFT float2 (128 KB)

    void* args[] = { (void*)&x, (void*)&y, (void*)&Lr, (void*)&Li,
                     (void*)&Pr, (void*)&Pi, (void*)&Br, (void*)&Bi,
                     (void*)&Cr, (void*)&Ci, (void*)&st,
                     (void*)&Kperm, (void*)&twid };
    hipLaunchCooperativeKernel((void*)s4_all, dim3(blocks), dim3(NTHREADS),
                               args, 0, stream);
}

// Round 12
// 66.646 us; speedup vs baseline: 2.7397x; 2.7397x over previous
//
#include <hip/hip_runtime.h>
#include <math.h>

#define LFFT 16384
#define NTHREADS 1024
#define LDS_PITCH 17   // float2 per row (16 + 1 pad); stride 34 banks == 2 mod 32

// Wave-local LDS ordering fence.
#define LDS_FENCE() asm volatile("s_waitcnt lgkmcnt(0)" ::: "memory")

__device__ __forceinline__ float2 cadd(float2 a, float2 b){ return make_float2(a.x+b.x, a.y+b.y); }
__device__ __forceinline__ float2 csub(float2 a, float2 b){ return make_float2(a.x-b.x, a.y-b.y); }
__device__ __forceinline__ float2 cmul(float2 a, float2 b){ return make_float2(a.x*b.x - a.y*b.y, a.x*b.y + a.y*b.x); }

template<int S> __device__ __forceinline__ float2 mul_is(float2 a) {
    return make_float2(-(float)S * a.y, (float)S * a.x);
}

// Radix-4 butterfly. S=-1 fwd, S=+1 inverse (unnormalized).
template<int S> __device__ __forceinline__ void dft4_t(float2& a0, float2& a1, float2& a2, float2& a3) {
    float2 t0 = cadd(a0, a2);
    float2 t1 = csub(a0, a2);
    float2 t2 = cadd(a1, a3);
    float2 t3 = csub(a1, a3);
    a0 = cadd(t0, t2);
    a2 = csub(t0, t2);
    const float s = (float)S;
    a1 = make_float2(t1.x - s * t3.y, t1.y + s * t3.x);
    a3 = make_float2(t1.x + s * t3.y, t1.y - s * t3.x);
}

#define C16A 0.92387953251128675613f
#define C16B 0.70710678118654752440f
#define C16C 0.38268343236508977173f

// Fully-unrolled 16-point DFT, natural order in and out.
template<int S> __device__ __forceinline__ void dft16_t(float2 r[16]) {
    const float s = (float)S;
    const float2 w1 = make_float2( C16A, s * C16C);
    const float2 w2 = make_float2( C16B, s * C16B);
    const float2 w3 = make_float2( C16C, s * C16A);
    const float2 w6 = make_float2(-C16B, s * C16B);
    const float2 w9 = make_float2(-C16A, -s * C16C);
    float2 g[4][4];
    #pragma unroll
    for (int b = 0; b < 4; ++b) {
        float2 a0 = r[b], a1 = r[b+4], a2 = r[b+8], a3 = r[b+12];
        dft4_t<S>(a0, a1, a2, a3);
        g[b][0] = a0; g[b][1] = a1; g[b][2] = a2; g[b][3] = a3;
    }
    g[1][1] = cmul(g[1][1], w1);  g[1][2] = cmul(g[1][2], w2);  g[1][3] = cmul(g[1][3], w3);
    g[2][1] = cmul(g[2][1], w2);  g[2][2] = mul_is<S>(g[2][2]); g[2][3] = cmul(g[2][3], w6);
    g[3][1] = cmul(g[3][1], w3);  g[3][2] = cmul(g[3][2], w6);  g[3][3] = cmul(g[3][3], w9);
    #pragma unroll
    for (int ka = 0; ka < 4; ++ka) {
        float2 a0 = g[0][ka], a1 = g[1][ka], a2 = g[2][ka], a3 = g[3][ka];
        dft4_t<S>(a0, a1, a2, a3);
        r[ka] = a0; r[ka+4] = a1; r[ka+8] = a2; r[ka+12] = a3;
    }
}

// r[k] *= w^k, k = 1..15
__device__ __forceinline__ void twiddle15(float2 r[16], float2 w) {
    float2 w2 = cmul(w, w);
    float2 we = w2;
    float2 wo = cmul(w, w2);
    r[1] = cmul(r[1], w);
    r[2] = cmul(r[2], we);
    r[3] = cmul(r[3], wo);
    #pragma unroll
    for (int j = 2; j <= 7; ++j) {
        we = cmul(we, w2);  r[2*j]   = cmul(r[2*j],   we);
        wo = cmul(wo, w2);  r[2*j+1] = cmul(r[2*j+1], wo);
    }
}

// ---------------------------------------------------------------------------
// Kernel 1: parallel table builder. 8 threads per output p:
//   e = which eval (0: K(m), 1: K(L-m)), q = which 16-state quarter of the
//   Cauchy sum. Half-angle identities (Omega = e^{-i phi}, phi = 2 pi m/L):
//     g = (2/step)(1-Omega)/(1+Omega) = i (2/step) tan(pi m / L)
//     c = 2/(1+Omega)                 = 1 + i tan(pi m / L)
//   One fp64 tan() replaces sincos + 2 complex divisions; per-thread
//   dependent chain is 16 loop iterations. Partials reduce through LDS;
//   lane (T&7)==0 finalizes both evals and Hermitian-combines:
//     Kperm[p] = 0.5/L (K(m) + conj(K(L-m))).
//   Lane (T&7)==1 emits twid[p] = cis(-2 pi p / L) in parallel.
// Output order matches the fft_conv (thread t16, slot j) multiply point:
//   p = t16*16 + j ; m = k1 + 16*k3 + 256*(4*k5h + k5l) + 4096*k6
// ---------------------------------------------------------------------------
__global__ void s4_tables(const float* __restrict__ Lr, const float* __restrict__ Li,
                          const float* __restrict__ Pr, const float* __restrict__ Pi,
                          const float* __restrict__ Br, const float* __restrict__ Bi,
                          const float* __restrict__ Cr, const float* __restrict__ Ci,
                          const float* __restrict__ step_ptr,
                          float2* __restrict__ Kperm, float2* __restrict__ twid)
{
    __shared__ double part[256][8];   // 16 KiB partial sums
    const int tid = threadIdx.x;
    const int T = blockIdx.x * 256 + tid;
    const int p = T >> 3, e = (T >> 2) & 1, q = T & 3;

    int t16 = p >> 4, j = p & 15;
    int m = (t16 >> 6) + 16 * ((t16 >> 2) & 15)
          + 256 * (4 * (t16 & 3) + (j >> 2)) + 4096 * (j & 3);
    int idx = e ? ((LFFT - m) & (LFFT - 1)) : m;

    const double step = (double)step_ptr[0];
    const double tn = tan((M_PI / (double)LFFT) * (double)idx);
    const double gi = (2.0 / step) * tn;   // g = i*gi (purely imaginary)

    double k00r=0,k00i=0,k01r=0,k01i=0,k10r=0,k10i=0,k11r=0,k11i=0;
    const int n0 = 16 * q;
    for (int n = n0; n < n0 + 16; ++n) {
        double dr = -(double)Lr[n];          // Re(g - Lambda), Re g = 0
        double di = gi - (double)Li[n];
        double id2 = 1.0 / (dr*dr + di*di);
        double vr =  dr * id2;               // inv = 1/(g - Lambda)
        double vi = -di * id2;
        double a0r = (double)Cr[n], a0i = -(double)Ci[n];   // conj(C)
        double a1r = (double)Pr[n], a1i = -(double)Pi[n];   // conj(P)
        double br  = (double)Br[n], bi  = (double)Bi[n];
        double pr  = (double)Pr[n], pi  = (double)Pi[n];
        double e00r = a0r*br - a0i*bi, e00i = a0r*bi + a0i*br;
        double e01r = a0r*pr - a0i*pi, e01i = a0r*pi + a0i*pr;
        double e10r = a1r*br - a1i*bi, e10i = a1r*bi + a1i*br;
        double e11r = a1r*pr - a1i*pi, e11i = a1r*pi + a1i*pr;
        k00r += vr*e00r - vi*e00i;  k00i += vr*e00i + vi*e00r;
        k01r += vr*e01r - vi*e01i;  k01i += vr*e01i + vi*e01r;
        k10r += vr*e10r - vi*e10i;  k10i += vr*e10i + vi*e10r;
        k11r += vr*e11r - vi*e11i;  k11i += vr*e11i + vi*e11r;
    }
    part[tid][0] = k00r;  part[tid][1] = k00i;
    part[tid][2] = k01r;  part[tid][3] = k01i;
    part[tid][4] = k10r;  part[tid][5] = k10i;
    part[tid][6] = k11r;  part[tid][7] = k11i;

    if ((T & 7) == 1) {   // twiddle table, hidden under the reduce path
        double tth = (-2.0 * M_PI / (double)LFFT) * (double)p;
        double si, co;
        sincos(tth, &si, &co);
        twid[p] = make_float2((float)co, (float)si);
    }
    __syncthreads();

    if ((T & 7) == 0) {
        double Kr[2], Ki[2];
        #pragma unroll
        for (int ev = 0; ev < 2; ++ev) {
            double s[8] = {0,0,0,0,0,0,0,0};
            #pragma unroll
            for (int qq = 0; qq < 4; ++qq) {
                const double* pp = part[tid + 4*ev + qq];
                #pragma unroll
                for (int z = 0; z < 8; ++z) s[z] += pp[z];
            }
            double rr = 1.0 + s[6], ri = s[7];
            double ir2 = 1.0 / (rr*rr + ri*ri);
            double qr0 = s[2]*s[4] - s[3]*s[5];
            double qi0 = s[2]*s[5] + s[3]*s[4];
            double qr = (qr0*rr + qi0*ri) * ir2;
            double qi = (qi0*rr - qr0*ri) * ir2;
            double sr = s[0] - qr, sim = s[1] - qi;
            // c = 1 + i*tc ;  tan(pi(L-m)/L) = -tan(pi m/L)
            double tc = (ev == 0) ? tn : -tn;
            Kr[ev] = sr - tc * sim;
            Ki[ev] = sim + tc * sr;
        }
        const float sc = 0.5f / (float)LFFT;
        Kperm[p] = make_float2(sc * (float)(Kr[0] + Kr[1]),
                               sc * (float)(Ki[0] - Ki[1]));
    }
}

// ---------------------------------------------------------------------------
// Kernel 2 (champion, verbatim): register-resident four-step FFT/IFFT
// (16384 = 16x16x16x4), two real rows packed as z = x0 + i*x1 per block.
// Wave-slip structure: T2/T3/IT3/IT2 are wave-local 64-row-stripe exchanges
// (lgkmcnt fences only); only T1/IT1 are cross-wave (3 barriers total).
// PITCH 17: every scatter write and own-row b64 read sits at the
// 4-lanes-per-bank-pair floor.
// ---------------------------------------------------------------------------
__global__ __launch_bounds__(NTHREADS, 4) void fft_conv(
    const float* __restrict__ x, float* __restrict__ y,
    const float2* __restrict__ twid, const float2* __restrict__ kperm)
{
    __shared__ float2 lds[NTHREADS * LDS_PITCH];   // 136 KiB
    const int t    = threadIdx.x;
    const int lane = t & 63;
    const int w    = t >> 6;
    const int l2   = t & 3;
    const int h    = (t >> 2) & 15;
    const size_t rowbase = (size_t)blockIdx.x * 2u * LFFT;
    const float* x0 = x + rowbase;
    const float* x1 = x0 + LFFT;

    float2 r[16];

    // ---- load: thread t owns n = t + 1024*a (coalesced) ----
    #pragma unroll
    for (int a = 0; a < 16; ++a)
        r[a] = make_float2(x0[t + NTHREADS*a], x1[t + NTHREADS*a]);

    // ---- P1: DFT-16 over a, twiddle W_16384^(t*k1) ----
    dft16_t<-1>(r);
    twiddle15(r, twid[t]);

    // ---- T1 (cross-wave): r[k] -> (row 64k+lane, col w); read own row ----
    #pragma unroll
    for (int k = 0; k < 16; ++k)
        lds[(k*64 + lane) * LDS_PITCH + w] = r[k];
    __syncthreads();
    #pragma unroll
    for (int a = 0; a < 16; ++a)
        r[a] = lds[t * LDS_PITCH + a];
    LDS_FENCE();   // my reads done before my T2 writes (same stripe)

    // ---- P2: DFT-16 over a2, twiddle W_1024^(lane*k3) ----
    dft16_t<-1>(r);
    twiddle15(r, twid[16 * lane]);

    // ---- T2 (wave-local stripe) ----
    #pragma unroll
    for (int k = 0; k < 16; ++k)
        lds[(w*64 + 4*k + l2) * LDS_PITCH + h] = r[k];
    LDS_FENCE();
    #pragma unroll
    for (int a = 0; a < 16; ++a)
        r[a] = lds[t * LDS_PITCH + a];
    LDS_FENCE();

    // ---- P3: DFT-16 over a3, twiddle W_64^(l2*k5) ----
    dft16_t<-1>(r);
    twiddle15(r, twid[256 * l2]);

    // ---- T3 (wave-local stripe) ----
    #pragma unroll
    for (int k = 0; k < 16; ++k)
        lds[((t & ~3) + (k >> 2)) * LDS_PITCH + 4*(k & 3) + l2] = r[k];
    LDS_FENCE();
    #pragma unroll
    for (int j = 0; j < 16; ++j)
        r[j] = lds[t * LDS_PITCH + j];
    LDS_FENCE();

    // ---- P4: DFT-4 over b3 ----
    #pragma unroll
    for (int q = 0; q < 4; ++q)
        dft4_t<-1>(r[4*q], r[4*q+1], r[4*q+2], r[4*q+3]);

    // ---- pointwise multiply (chunked) ----
    {
        const float4* kp4 = (const float4*)(kperm + t * 16);
        #pragma unroll
        for (int c = 0; c < 2; ++c) {
            float4 kv[4];
            #pragma unroll
            for (int i = 0; i < 4; ++i) kv[i] = kp4[4*c + i];
            #pragma unroll
            for (int i = 0; i < 4; ++i) {
                r[8*c + 2*i]     = cmul(r[8*c + 2*i],     make_float2(kv[i].x, kv[i].y));
                r[8*c + 2*i + 1] = cmul(r[8*c + 2*i + 1], make_float2(kv[i].z, kv[i].w));
            }
        }
    }

    // ---- IP4: inverse DFT-4 over k6 ----
    #pragma unroll
    for (int q = 0; q < 4; ++q)
        dft4_t<1>(r[4*q], r[4*q+1], r[4*q+2], r[4*q+3]);

    // ---- IT3 (wave-local stripe) ----
    #pragma unroll
    for (int j = 0; j < 16; ++j)
        lds[((t & ~3) + (j & 3)) * LDS_PITCH + ((4*l2 + (j >> 2)) ^ h)] = r[j];
    LDS_FENCE();
    #pragma unroll
    for (int k = 0; k < 16; ++k)
        r[k] = lds[t * LDS_PITCH + (k ^ h)];
    LDS_FENCE();

    // ---- IP3 ----
    { float2 ww = twid[256 * l2]; twiddle15(r, make_float2(ww.x, -ww.y)); }
    dft16_t<1>(r);

    // ---- IT2 (wave-local stripe) ----
    #pragma unroll
    for (int a = 0; a < 16; ++a)
        lds[(w*64 + l2 + 4*a) * LDS_PITCH + h] = r[a];
    LDS_FENCE();
    #pragma unroll
    for (int k = 0; k < 16; ++k)
        r[k] = lds[t * LDS_PITCH + k];

    // ---- IP2 ----
    { float2 ww = twid[16 * lane]; twiddle15(r, make_float2(ww.x, -ww.y)); }
    dft16_t<1>(r);

    // ---- IT1 (cross-wave): wait all waves' IT2 reads, then exchange ----
    __syncthreads();
    #pragma unroll
    for (int a = 0; a < 16; ++a)
        lds[(lane + 64*a) * LDS_PITCH + w] = r[a];
    __syncthreads();
    #pragma unroll
    for (int k = 0; k < 16; ++k)
        r[k] = lds[t * LDS_PITCH + k];

    // ---- IP1 ----
    { float2 ww = twid[t]; twiddle15(r, make_float2(ww.x, -ww.y)); }
    dft16_t<1>(r);

    // ---- store: Re -> row0, Im -> row1 (coalesced) ----
    float* y0 = y + rowbase;
    float* y1 = y0 + LFFT;
    #pragma unroll
    for (int a = 0; a < 16; ++a) {
        y0[t + NTHREADS*a] = r[a].x;
        y1[t + NTHREADS*a] = r[a].y;
    }
}

extern "C" void kernel_launch(void* const* d_in, const int* in_sizes, int n_in,
                              void* d_out, int out_size, void* d_ws, size_t ws_size,
                              hipStream_t stream)
{
    const float* x  = (const float*)d_in[0];
    const float* Lr = (const float*)d_in[1];
    const float* Li = (const float*)d_in[2];
    const float* Pr = (const float*)d_in[3];
    const float* Pi = (const float*)d_in[4];
    const float* Br = (const float*)d_in[5];
    const float* Bi = (const float*)d_in[6];
    const float* Cr = (const float*)d_in[7];
    const float* Ci = (const float*)d_in[8];
    const float* st = (const float*)d_in[9];

    const int rows = in_sizes[0] / LFFT;   // 1024

    float2* twid  = (float2*)d_ws;          // LFFT float2 (128 KB)
    float2* Kperm = twid + LFFT;            // LFFT float2 (128 KB)

    s4_tables<<<(8 * LFFT) / 256, 256, 0, stream>>>(Lr, Li, Pr, Pi, Br, Bi,
                                                    Cr, Ci, st, Kperm, twid);
    fft_conv<<<rows / 2, NTHREADS, 0, stream>>>(x, (float*)d_out, twid, Kperm);
}